// Round 2
// baseline (4792.108 us; speedup 1.0000x reference)
//
#include <hip/hip_runtime.h>
#include <hip/hip_bf16.h>

// Problem constants (B=8, S=256, D=64, G=32, E=256, L=4, NH=8, DH=8)
constexpr int kB  = 8;
constexpr int kS  = 256;
constexpr int kD  = 64;
constexpr int kG  = 32;
constexpr int kE  = 256;
constexpr int kNH = 8;
constexpr int kHD = 256;              // DH*G = 8*32
constexpr int kDG = kD * kG;          // 2048
constexpr int kT  = kB * kS;          // 2048 tokens
constexpr int kNC = 1000;

// ---------------- copy input residual stream into mutable ws ----------------
__global__ __launch_bounds__(256) void copy_kernel(const float* __restrict__ in,
                                                   float* __restrict__ out, int n) {
    int i = blockIdx.x * 256 + threadIdx.x;
    if (i < n) out[i] = in[i];
}

// ---------------- layer_norm2d over (D,G) per token ----------------
__global__ __launch_bounds__(256) void ln2d_kernel(const float* __restrict__ X,
                                                   const float* __restrict__ w,
                                                   const float* __restrict__ b,
                                                   float* __restrict__ Out) {
    int t = blockIdx.x, tid = threadIdx.x;
    const float* xp = X + (size_t)t * kDG;
    __shared__ float r1[256], r2[256];
    float v[8], s = 0.f, ss = 0.f;
#pragma unroll
    for (int j = 0; j < 8; j++) {
        float x = xp[tid + j * 256];
        v[j] = x; s += x; ss += x * x;
    }
    r1[tid] = s; r2[tid] = ss; __syncthreads();
    for (int o = 128; o > 0; o >>= 1) {
        if (tid < o) { r1[tid] += r1[tid + o]; r2[tid] += r2[tid + o]; }
        __syncthreads();
    }
    float mean = r1[0] * (1.f / kDG);
    float var  = r2[0] * (1.f / kDG) - mean * mean;
    float rstd = rsqrtf(var + 1e-5f);
    float* op = Out + (size_t)t * kDG;
#pragma unroll
    for (int j = 0; j < 8; j++) {
        int jj = tid + j * 256;
        op[jj] = (v[j] - mean) * rstd * w[jj] + b[jj];
    }
}

// ---------------- versor_linear: out[t,o,g] = sum_i W[o,i]*x[t,i,g] + b[o,g]
// I = O = 64. One block per token.
__global__ __launch_bounds__(256) void vlin_kernel(const float* __restrict__ X,
                                                   const float* __restrict__ W,
                                                   const float* __restrict__ bias,
                                                   float* __restrict__ Out) {
    __shared__ float sx[kDG];      // 8 KB
    __shared__ float sw[kD * kD];  // 16 KB
    int t = blockIdx.x, tid = threadIdx.x;
    const float* xp = X + (size_t)t * kDG;
    for (int j = tid; j < kDG; j += 256) sx[j] = xp[j];
    for (int j = tid; j < kD * kD; j += 256) sw[j] = W[j];
    __syncthreads();
    int g = tid & 31, ob = tid >> 5;
    float* op = Out + (size_t)t * kDG;
    for (int o = ob; o < kD; o += 8) {
        float acc = bias[o * kG + g];
        const float* wr = sw + o * kD;
#pragma unroll
        for (int i = 0; i < kD; i++) acc += wr[i] * sx[i * kG + g];
        op[o * kG + g] = acc;
    }
}

// ---------------- attention: one block per (s,h,b) ----------------
__global__ __launch_bounds__(256) void attn_kernel(const float* __restrict__ Q,
                                                   const float* __restrict__ K,
                                                   const float* __restrict__ V,
                                                   float* __restrict__ O) {
    int s = blockIdx.x, h = blockIdx.y, b = blockIdx.z, tid = threadIdx.x;
    __shared__ float qs[256], sc[256], red[256];
    size_t qoff = ((size_t)(b * kS + s)) * kDG + h * kHD;
    qs[tid] = Q[qoff + tid];
    __syncthreads();
    // scores: thread tid = key position
    size_t koff = ((size_t)(b * kS + tid)) * kDG + h * kHD;
    float acc = 0.f;
#pragma unroll 8
    for (int j = 0; j < kHD; j++) acc += qs[j] * K[koff + j];
    float sco = acc * 0.0625f;   // 1/sqrt(dh*G) = 1/16
    red[tid] = sco; __syncthreads();
    for (int o = 128; o > 0; o >>= 1) {
        if (tid < o) red[tid] = fmaxf(red[tid], red[tid + o]);
        __syncthreads();
    }
    float m = red[0]; __syncthreads();
    float e = __expf(sco - m);
    sc[tid] = e;
    red[tid] = e; __syncthreads();
    for (int o = 128; o > 0; o >>= 1) {
        if (tid < o) red[tid] += red[tid + o];
        __syncthreads();
    }
    float inv = 1.f / red[0];
    // PV: thread tid = output dim
    float oacc = 0.f;
    for (int tk = 0; tk < kS; tk++)
        oacc += sc[tk] * V[((size_t)(b * kS + tk)) * kDG + h * kHD + tid];
    O[qoff + tid] = oacc * inv;
}

// ---------------- residual + manifold_norm: X = mn(X + gamma*H) ----------------
__global__ __launch_bounds__(256) void resmn_kernel(float* __restrict__ X,
                                                    const float* __restrict__ H,
                                                    const float* __restrict__ gamma) {
    int gid = blockIdx.x * 8 + (threadIdx.x >> 5);
    int lane = threadIdx.x & 31;
    int d = gid % kD;
    size_t idx = (size_t)gid * kG + lane;
    float v = X[idx] + gamma[d * kG + lane] * H[idx];
    float sq = v * v;
#pragma unroll
    for (int m = 16; m > 0; m >>= 1) sq += __shfl_xor(sq, m, 32);
    X[idx] = v / (sqrtf(sq) + 1e-6f);
}

// ---------------- fused MLP per token: out = W2 tanh(W1 x + b1) + b2 ----------------
__global__ __launch_bounds__(256) void mlp_kernel(const float* __restrict__ X,
                                                  const float* __restrict__ W1,
                                                  const float* __restrict__ b1,
                                                  const float* __restrict__ W2,
                                                  const float* __restrict__ b2,
                                                  float* __restrict__ Out) {
    __shared__ float sx[kDG];        // 8 KB
    __shared__ float sm[kE * kG];    // 32 KB
    int t = blockIdx.x, tid = threadIdx.x;
    const float* xp = X + (size_t)t * kDG;
    for (int j = tid; j < kDG; j += 256) sx[j] = xp[j];
    __syncthreads();
    int g = tid & 31, eb = tid >> 5;
    for (int e = eb; e < kE; e += 8) {
        float acc = b1[e * kG + g];
        const float* w = W1 + e * kD;
#pragma unroll
        for (int i = 0; i < kD; i++) acc += w[i] * sx[i * kG + g];
        sm[e * kG + g] = tanhf(acc);
    }
    __syncthreads();
    float* op = Out + (size_t)t * kDG;
    for (int o = eb; o < kD; o += 8) {
        float acc = b2[o * kG + g];
        const float* w = W2 + o * kE;
#pragma unroll 8
        for (int e = 0; e < kE; e++) acc += w[e] * sm[e * kG + g];
        op[o * kG + g] = acc;
    }
}

// ---------------- rot init: R = mn(0.5*delta + e0) ----------------
__global__ __launch_bounds__(256) void rotinit_kernel(const float* __restrict__ A,
                                                      float* __restrict__ R) {
    int gid = blockIdx.x * 8 + (threadIdx.x >> 5);
    int lane = threadIdx.x & 31;
    size_t idx = (size_t)gid * kG + lane;
    float v = 0.5f * A[idx] + (lane == 0 ? 1.0f : 0.0f);
    float sq = v * v;
#pragma unroll
    for (int m = 16; m > 0; m >>= 1) sq += __shfl_xor(sq, m, 32);
    R[idx] = v / (sqrtf(sq) + 1e-6f);
}

// ---------------- scan step: Out[s] = s<step ? In[s] : mn(gp(In[s], In[s-step]))
__global__ __launch_bounds__(256) void scan_kernel(const float* __restrict__ In,
                                                   float* __restrict__ Out, int step) {
    __shared__ float sgn[1024];
    int tid = threadIdx.x;
    for (int q = tid; q < 1024; q += 256) {
        int a = q >> 5, k = q & 31, bb = a ^ k;
        int ssum = 0;
        for (int tt = a >> 1; tt; tt >>= 1) ssum += __popc(tt & bb);
        ssum += (a & bb) >> 4;          // SIG[4] = -1 metric term
        sgn[q] = (ssum & 1) ? -1.f : 1.f;
    }
    __syncthreads();
    int gid = blockIdx.x * 8 + (tid >> 5);
    int lane = tid & 31;
    int s = (gid / kD) % kS;
    size_t idx = (size_t)gid * kG + lane;
    float xk = In[idx];
    if (s < step) { Out[idx] = xk; return; }
    float yk = In[idx - (size_t)step * kDG];
    float acc = 0.f;
#pragma unroll
    for (int a = 0; a < 32; a++) {
        float xa = __shfl(xk, a, 32);
        float yb = __shfl(yk, a ^ lane, 32);
        acc += sgn[a * 32 + lane] * xa * yb;
    }
    float sq = acc * acc;
#pragma unroll
    for (int m = 16; m > 0; m >>= 1) sq += __shfl_xor(sq, m, 32);
    Out[idx] = acc / (sqrtf(sq) + 1e-6f);
}

// ---------------- classifier: logits = pooled @ Wc^T + bc ----------------
__global__ __launch_bounds__(256) void cls_kernel(const float* __restrict__ R,
                                                  const float* __restrict__ Wc,
                                                  const float* __restrict__ bc,
                                                  float* __restrict__ out) {
    int idx = blockIdx.x * 256 + threadIdx.x;
    if (idx >= kB * kNC) return;
    int b = idx / kNC, c = idx % kNC;
    const float* p = R + ((size_t)(b * kS + kS - 1)) * kDG;
    const float* w = Wc + (size_t)c * kDG;
    float acc = bc[c];
#pragma unroll 8
    for (int j = 0; j < kDG; j++) acc += p[j] * w[j];
    out[idx] = acc;
}

extern "C" void kernel_launch(void* const* d_in, const int* in_sizes, int n_in,
                              void* d_out, int out_size, void* d_ws, size_t ws_size,
                              hipStream_t stream) {
    const float* x_in = (const float*)d_in[0];
    const float* Wq   = (const float*)d_in[1];
    const float* bq   = (const float*)d_in[2];
    const float* Wk   = (const float*)d_in[3];
    const float* bk   = (const float*)d_in[4];
    const float* Wv   = (const float*)d_in[5];
    const float* bv   = (const float*)d_in[6];
    const float* Wo   = (const float*)d_in[7];
    const float* bo   = (const float*)d_in[8];
    const float* ln1w = (const float*)d_in[9];
    const float* ln1b = (const float*)d_in[10];
    const float* ln2w = (const float*)d_in[11];
    const float* ln2b = (const float*)d_in[12];
    const float* gm1  = (const float*)d_in[13];
    const float* gm2  = (const float*)d_in[14];
    const float* W1   = (const float*)d_in[15];
    const float* b1   = (const float*)d_in[16];
    const float* W2   = (const float*)d_in[17];
    const float* b2   = (const float*)d_in[18];
    const float* Wr   = (const float*)d_in[19];
    const float* br   = (const float*)d_in[20];
    const float* Wc   = (const float*)d_in[21];
    const float* bc   = (const float*)d_in[22];

    const size_t NEL = (size_t)kT * kDG;   // 4M elements per activation buffer
    float* F  = (float*)d_ws;
    float* X  = F;
    float* A  = F + NEL;
    float* Qb = F + 2 * NEL;
    float* Kb = F + 3 * NEL;
    float* Vb = F + 4 * NEL;

    copy_kernel<<<(int)(NEL / 256), 256, 0, stream>>>(x_in, X, (int)NEL);

    for (int l = 0; l < 4; l++) {
        ln2d_kernel<<<kT, 256, 0, stream>>>(X, ln1w + l * kDG, ln1b + l * kDG, A);
        vlin_kernel<<<kT, 256, 0, stream>>>(A, Wq + l * kD * kD, bq + l * kDG, Qb);
        vlin_kernel<<<kT, 256, 0, stream>>>(A, Wk + l * kD * kD, bk + l * kDG, Kb);
        vlin_kernel<<<kT, 256, 0, stream>>>(A, Wv + l * kD * kD, bv + l * kDG, Vb);
        attn_kernel<<<dim3(kS, kNH, kB), 256, 0, stream>>>(Qb, Kb, Vb, A);
        vlin_kernel<<<kT, 256, 0, stream>>>(A, Wo + l * kD * kD, bo + l * kDG, Qb);
        resmn_kernel<<<kT * kD / 8, 256, 0, stream>>>(X, Qb, gm1 + l * kDG);
        ln2d_kernel<<<kT, 256, 0, stream>>>(X, ln2w + l * kDG, ln2b + l * kDG, A);
        mlp_kernel<<<kT, 256, 0, stream>>>(A, W1 + l * kE * kD, b1 + l * kE * kG,
                                           W2 + l * kD * kE, b2 + l * kDG, Qb);
        resmn_kernel<<<kT * kD / 8, 256, 0, stream>>>(X, Qb, gm2 + l * kDG);
    }

    // delta / rot init / scan
    vlin_kernel<<<kT, 256, 0, stream>>>(X, Wr, br, A);
    rotinit_kernel<<<kT * kD / 8, 256, 0, stream>>>(A, Kb);
    float* pin = Kb;
    float* pout = Vb;
    for (int step = 1; step < kS; step <<= 1) {
        scan_kernel<<<kT * kD / 8, 256, 0, stream>>>(pin, pout, step);
        float* tmp = pin; pin = pout; pout = tmp;
    }
    // after 8 steps (step=1..128), pin == Kb
    cls_kernel<<<(kB * kNC + 255) / 256, 256, 0, stream>>>(pin, Wc, bc, (float*)d_out);
}

// Round 3
// 2130.471 us; speedup vs baseline: 2.2493x; 2.2493x over previous
//
#include <hip/hip_runtime.h>
#include <hip/hip_bf16.h>

// Problem constants (B=8, S=256, D=64, G=32, E=256, L=4, NH=8, DH=8)
constexpr int kB  = 8;
constexpr int kS  = 256;
constexpr int kD  = 64;
constexpr int kG  = 32;
constexpr int kE  = 256;
constexpr int kNH = 8;
constexpr int kHD = 256;              // DH*G = 8*32
constexpr int kDG = kD * kG;          // 2048
constexpr int kT  = kB * kS;          // 2048 tokens
constexpr int kNC = 1000;

using bf16x8 = __attribute__((ext_vector_type(8))) short;
using f32x4  = __attribute__((ext_vector_type(4))) float;

__device__ __forceinline__ short f2bf(float f) {
    unsigned u = __float_as_uint(f);
    unsigned r = (u + 0x7FFFu + ((u >> 16) & 1u)) >> 16;   // RNE
    return (short)r;
}

// ---------------- copy input residual stream into mutable ws ----------------
__global__ __launch_bounds__(256) void copy_kernel(const float* __restrict__ in,
                                                   float* __restrict__ out, int n) {
    int i = blockIdx.x * 256 + threadIdx.x;
    if (i < n) out[i] = in[i];
}

// ---------------- layer_norm2d over (D,G) per token ----------------
__global__ __launch_bounds__(256) void ln2d_kernel(const float* __restrict__ X,
                                                   const float* __restrict__ w,
                                                   const float* __restrict__ b,
                                                   float* __restrict__ Out) {
    int t = blockIdx.x, tid = threadIdx.x;
    const float* xp = X + (size_t)t * kDG;
    __shared__ float r1[256], r2[256];
    float v[8], s = 0.f, ss = 0.f;
#pragma unroll
    for (int j = 0; j < 8; j++) {
        float x = xp[tid + j * 256];
        v[j] = x; s += x; ss += x * x;
    }
    r1[tid] = s; r2[tid] = ss; __syncthreads();
    for (int o = 128; o > 0; o >>= 1) {
        if (tid < o) { r1[tid] += r1[tid + o]; r2[tid] += r2[tid + o]; }
        __syncthreads();
    }
    float mean = r1[0] * (1.f / kDG);
    float var  = r2[0] * (1.f / kDG) - mean * mean;
    float rstd = rsqrtf(var + 1e-5f);
    float* op = Out + (size_t)t * kDG;
#pragma unroll
    for (int j = 0; j < 8; j++) {
        int jj = tid + j * 256;
        op[jj] = (v[j] - mean) * rstd * w[jj] + b[jj];
    }
}

// ---------------- versor_linear: out[t,o,g] = sum_i W[o,i]*x[t,i,g] + b[o,g]
__global__ __launch_bounds__(256) void vlin_kernel(const float* __restrict__ X,
                                                   const float* __restrict__ W,
                                                   const float* __restrict__ bias,
                                                   float* __restrict__ Out) {
    __shared__ float sx[kDG];      // 8 KB
    __shared__ float sw[kD * kD];  // 16 KB
    int t = blockIdx.x, tid = threadIdx.x;
    const float* xp = X + (size_t)t * kDG;
    for (int j = tid; j < kDG; j += 256) sx[j] = xp[j];
    for (int j = tid; j < kD * kD; j += 256) sw[j] = W[j];
    __syncthreads();
    int g = tid & 31, ob = tid >> 5;
    float* op = Out + (size_t)t * kDG;
    for (int o = ob; o < kD; o += 8) {
        float acc = bias[o * kG + g];
        const float* wr = sw + o * kD;
#pragma unroll
        for (int i = 0; i < kD; i++) acc += wr[i] * sx[i * kG + g];
        op[o * kG + g] = acc;
    }
}

// ---------------- MFMA flash-style attention ----------------
// Block = 256 threads (4 waves), handles (b, h, 64-query tile).
// Wave w owns q rows [w*16, w*16+16). Full 256-key scores kept in registers.
constexpr int QSTR = 264;   // bf16 row stride for Qs/Ps and K tiles (16B-aligned, 2-way max)
constexpr int VSTR = 40;    // bf16 row stride for VsT (32 keys + 8 pad)

__global__ __launch_bounds__(256) void attn_mfma_kernel(const float* __restrict__ Q,
                                                        const float* __restrict__ K,
                                                        const float* __restrict__ V,
                                                        float* __restrict__ O) {
    __shared__ short sQ[64 * QSTR];          // Q tile, later reused for P (bf16)
    __shared__ short sKV[256 * VSTR];        // K tiles [32][QSTR] (8448) / VsT [256][VSTR] (10240)

    const int qt = blockIdx.x, h = blockIdx.y, b = blockIdx.z;
    const int tid = threadIdx.x;
    const int wave = tid >> 6, lane = tid & 63;
    const int l16 = lane & 15, quad = lane >> 4;

    const size_t bh = (size_t)b * kS * kDG + (size_t)h * kHD;  // + t*kDG + d

    // ---- stage Q tile (rows qt*64..+63, 256 dims) fp32->bf16, coalesced ----
    {
        int r0 = tid >> 6;               // 4 rows per pass
        int c4 = lane << 2;              // dim (float4 granule)
        for (int it = 0; it < 16; ++it) {
            int row = it * 4 + r0;
            const float4 v = *(const float4*)(Q + bh + (size_t)(qt * 64 + row) * kDG + c4);
            short4 p = make_short4(f2bf(v.x), f2bf(v.y), f2bf(v.z), f2bf(v.w));
            *(short4*)&sQ[row * QSTR + c4] = p;
        }
    }
    __syncthreads();

    // ---- Q A-fragments (held in registers for whole score phase) ----
    bf16x8 afrag[8];
    {
        int row = wave * 16 + l16;
#pragma unroll
        for (int c = 0; c < 8; ++c)
            afrag[c] = *(const bf16x8*)&sQ[row * QSTR + c * 32 + quad * 8];
    }

    // ---- scores: S[16q x 256k] per wave, 16 C-frags ----
    f32x4 acc[16];
#pragma unroll
    for (int i = 0; i < 16; ++i) acc[i] = (f32x4){0.f, 0.f, 0.f, 0.f};

    for (int kt = 0; kt < 8; ++kt) {
        __syncthreads();   // previous tile fully consumed
        {
            int r0 = tid >> 6;
            int c4 = lane << 2;
            for (int it = 0; it < 8; ++it) {
                int row = it * 4 + r0;
                const float4 v = *(const float4*)(K + bh + (size_t)(kt * 32 + row) * kDG + c4);
                short4 p = make_short4(f2bf(v.x), f2bf(v.y), f2bf(v.z), f2bf(v.w));
                *(short4*)&sKV[row * QSTR + c4] = p;
            }
        }
        __syncthreads();
#pragma unroll
        for (int nt = 0; nt < 2; ++nt) {
            int key = nt * 16 + l16;
            f32x4 a = acc[kt * 2 + nt];
#pragma unroll
            for (int c = 0; c < 8; ++c) {
                bf16x8 bfrag = *(const bf16x8*)&sKV[key * QSTR + c * 32 + quad * 8];
                a = __builtin_amdgcn_mfma_f32_16x16x32_bf16(afrag[c], bfrag, a, 0, 0, 0);
            }
            acc[kt * 2 + nt] = a;
        }
    }
    __syncthreads();

    // ---- softmax across full 256 keys (rows = quad*4 + r) ----
    float inv[4];
#pragma unroll
    for (int r = 0; r < 4; ++r) {
        float m = -1e30f;
#pragma unroll
        for (int t = 0; t < 16; ++t) m = fmaxf(m, acc[t][r]);
#pragma unroll
        for (int off = 1; off < 16; off <<= 1) m = fmaxf(m, __shfl_xor(m, off, 16));
        float s = 0.f;
#pragma unroll
        for (int t = 0; t < 16; ++t) {
            float p = __expf((acc[t][r] - m) * 0.0625f);   // scale = 1/sqrt(256)
            acc[t][r] = p; s += p;
        }
#pragma unroll
        for (int off = 1; off < 16; off <<= 1) s += __shfl_xor(s, off, 16);
        inv[r] = 1.f / s;
    }

    // ---- write P (bf16) into sQ (Q frags already live in registers) ----
#pragma unroll
    for (int t = 0; t < 16; ++t)
#pragma unroll
        for (int r = 0; r < 4; ++r)
            sQ[(wave * 16 + quad * 4 + r) * QSTR + t * 16 + l16] = f2bf(acc[t][r]);

    // ---- PV: O[16q x 256d] per wave ----
    f32x4 oacc[16];
#pragma unroll
    for (int i = 0; i < 16; ++i) oacc[i] = (f32x4){0.f, 0.f, 0.f, 0.f};

    for (int vt = 0; vt < 8; ++vt) {
        __syncthreads();   // P writes done (vt=0) / previous V tile consumed
        // stage V^T tile: VsT[d][key_local], 4x4 register-block transpose
        {
            int kb = tid >> 5;                 // 0..7  -> keys kb*4..+3
            for (int it = 0; it < 2; ++it) {
                int db = (tid & 31) + it * 32; // 0..63 -> dims db*4..+3
                float4 vr[4];
#pragma unroll
                for (int r = 0; r < 4; ++r)
                    vr[r] = *(const float4*)(V + bh + (size_t)(vt * 32 + kb * 4 + r) * kDG + db * 4);
#pragma unroll
                for (int i = 0; i < 4; ++i) {
                    short4 p = make_short4(f2bf(vr[0][i]), f2bf(vr[1][i]),
                                           f2bf(vr[2][i]), f2bf(vr[3][i]));
                    *(short4*)&sKV[(db * 4 + i) * VSTR + kb * 4] = p;
                }
            }
        }
        __syncthreads();
        bf16x8 pfrag = *(const bf16x8*)&sQ[(wave * 16 + l16) * QSTR + vt * 32 + quad * 8];
#pragma unroll
        for (int dt = 0; dt < 16; ++dt) {
            bf16x8 vfrag = *(const bf16x8*)&sKV[(dt * 16 + l16) * VSTR + quad * 8];
            oacc[dt] = __builtin_amdgcn_mfma_f32_16x16x32_bf16(pfrag, vfrag, oacc[dt], 0, 0, 0);
        }
    }

    // ---- epilogue: scale by 1/rowsum, write fp32 ----
    {
        int qrow = qt * 64 + wave * 16 + quad * 4;
#pragma unroll
        for (int dt = 0; dt < 16; ++dt)
#pragma unroll
            for (int r = 0; r < 4; ++r)
                O[bh + (size_t)(qrow + r) * kDG + dt * 16 + l16] = oacc[dt][r] * inv[r];
    }
}

// ---------------- residual + manifold_norm: X = mn(X + gamma*H) ----------------
__global__ __launch_bounds__(256) void resmn_kernel(float* __restrict__ X,
                                                    const float* __restrict__ H,
                                                    const float* __restrict__ gamma) {
    int gid = blockIdx.x * 8 + (threadIdx.x >> 5);
    int lane = threadIdx.x & 31;
    int d = gid % kD;
    size_t idx = (size_t)gid * kG + lane;
    float v = X[idx] + gamma[d * kG + lane] * H[idx];
    float sq = v * v;
#pragma unroll
    for (int m = 16; m > 0; m >>= 1) sq += __shfl_xor(sq, m, 32);
    X[idx] = v / (sqrtf(sq) + 1e-6f);
}

// ---------------- fused MLP per token: out = W2 tanh(W1 x + b1) + b2 ----------------
__global__ __launch_bounds__(256) void mlp_kernel(const float* __restrict__ X,
                                                  const float* __restrict__ W1,
                                                  const float* __restrict__ b1,
                                                  const float* __restrict__ W2,
                                                  const float* __restrict__ b2,
                                                  float* __restrict__ Out) {
    __shared__ float sx[kDG];        // 8 KB
    __shared__ float sm[kE * kG];    // 32 KB
    int t = blockIdx.x, tid = threadIdx.x;
    const float* xp = X + (size_t)t * kDG;
    for (int j = tid; j < kDG; j += 256) sx[j] = xp[j];
    __syncthreads();
    int g = tid & 31, eb = tid >> 5;
    for (int e = eb; e < kE; e += 8) {
        float acc = b1[e * kG + g];
        const float* w = W1 + e * kD;
#pragma unroll
        for (int i = 0; i < kD; i++) acc += w[i] * sx[i * kG + g];
        sm[e * kG + g] = tanhf(acc);
    }
    __syncthreads();
    float* op = Out + (size_t)t * kDG;
    for (int o = eb; o < kD; o += 8) {
        float acc = b2[o * kG + g];
        const float* w = W2 + o * kE;
#pragma unroll 8
        for (int e = 0; e < kE; e++) acc += w[e] * sm[e * kG + g];
        op[o * kG + g] = acc;
    }
}

// ---------------- rot init: R = mn(0.5*delta + e0) ----------------
__global__ __launch_bounds__(256) void rotinit_kernel(const float* __restrict__ A,
                                                      float* __restrict__ R) {
    int gid = blockIdx.x * 8 + (threadIdx.x >> 5);
    int lane = threadIdx.x & 31;
    size_t idx = (size_t)gid * kG + lane;
    float v = 0.5f * A[idx] + (lane == 0 ? 1.0f : 0.0f);
    float sq = v * v;
#pragma unroll
    for (int m = 16; m > 0; m >>= 1) sq += __shfl_xor(sq, m, 32);
    R[idx] = v / (sqrtf(sq) + 1e-6f);
}

// ---------------- scan step: Out[s] = s<step ? In[s] : mn(gp(In[s], In[s-step]))
__global__ __launch_bounds__(256) void scan_kernel(const float* __restrict__ In,
                                                   float* __restrict__ Out, int step) {
    __shared__ float sgn[1024];
    int tid = threadIdx.x;
    for (int q = tid; q < 1024; q += 256) {
        int a = q >> 5, k = q & 31, bb = a ^ k;
        int ssum = 0;
        for (int tt = a >> 1; tt; tt >>= 1) ssum += __popc(tt & bb);
        ssum += (a & bb) >> 4;          // SIG[4] = -1 metric term
        sgn[q] = (ssum & 1) ? -1.f : 1.f;
    }
    __syncthreads();
    int gid = blockIdx.x * 8 + (tid >> 5);
    int lane = tid & 31;
    int s = (gid / kD) % kS;
    size_t idx = (size_t)gid * kG + lane;
    float xk = In[idx];
    if (s < step) { Out[idx] = xk; return; }
    float yk = In[idx - (size_t)step * kDG];
    float acc = 0.f;
#pragma unroll
    for (int a = 0; a < 32; a++) {
        float xa = __shfl(xk, a, 32);
        float yb = __shfl(yk, a ^ lane, 32);
        acc += sgn[a * 32 + lane] * xa * yb;
    }
    float sq = acc * acc;
#pragma unroll
    for (int m = 16; m > 0; m >>= 1) sq += __shfl_xor(sq, m, 32);
    Out[idx] = acc / (sqrtf(sq) + 1e-6f);
}

// ---------------- classifier: logits = pooled @ Wc^T + bc ----------------
__global__ __launch_bounds__(256) void cls_kernel(const float* __restrict__ R,
                                                  const float* __restrict__ Wc,
                                                  const float* __restrict__ bc,
                                                  float* __restrict__ out) {
    int idx = blockIdx.x * 256 + threadIdx.x;
    if (idx >= kB * kNC) return;
    int b = idx / kNC, c = idx % kNC;
    const float* p = R + ((size_t)(b * kS + kS - 1)) * kDG;
    const float* w = Wc + (size_t)c * kDG;
    float acc = bc[c];
#pragma unroll 8
    for (int j = 0; j < kDG; j++) acc += p[j] * w[j];
    out[idx] = acc;
}

extern "C" void kernel_launch(void* const* d_in, const int* in_sizes, int n_in,
                              void* d_out, int out_size, void* d_ws, size_t ws_size,
                              hipStream_t stream) {
    const float* x_in = (const float*)d_in[0];
    const float* Wq   = (const float*)d_in[1];
    const float* bq   = (const float*)d_in[2];
    const float* Wk   = (const float*)d_in[3];
    const float* bk   = (const float*)d_in[4];
    const float* Wv   = (const float*)d_in[5];
    const float* bv   = (const float*)d_in[6];
    const float* Wo   = (const float*)d_in[7];
    const float* bo   = (const float*)d_in[8];
    const float* ln1w = (const float*)d_in[9];
    const float* ln1b = (const float*)d_in[10];
    const float* ln2w = (const float*)d_in[11];
    const float* ln2b = (const float*)d_in[12];
    const float* gm1  = (const float*)d_in[13];
    const float* gm2  = (const float*)d_in[14];
    const float* W1   = (const float*)d_in[15];
    const float* b1   = (const float*)d_in[16];
    const float* W2   = (const float*)d_in[17];
    const float* b2   = (const float*)d_in[18];
    const float* Wr   = (const float*)d_in[19];
    const float* br   = (const float*)d_in[20];
    const float* Wc   = (const float*)d_in[21];
    const float* bc   = (const float*)d_in[22];

    const size_t NEL = (size_t)kT * kDG;   // 4M elements per activation buffer
    float* F  = (float*)d_ws;
    float* X  = F;
    float* A  = F + NEL;
    float* Qb = F + 2 * NEL;
    float* Kb = F + 3 * NEL;
    float* Vb = F + 4 * NEL;

    copy_kernel<<<(int)(NEL / 256), 256, 0, stream>>>(x_in, X, (int)NEL);

    for (int l = 0; l < 4; l++) {
        ln2d_kernel<<<kT, 256, 0, stream>>>(X, ln1w + l * kDG, ln1b + l * kDG, A);
        vlin_kernel<<<kT, 256, 0, stream>>>(A, Wq + l * kD * kD, bq + l * kDG, Qb);
        vlin_kernel<<<kT, 256, 0, stream>>>(A, Wk + l * kD * kD, bk + l * kDG, Kb);
        vlin_kernel<<<kT, 256, 0, stream>>>(A, Wv + l * kD * kD, bv + l * kDG, Vb);
        attn_mfma_kernel<<<dim3(4, kNH, kB), 256, 0, stream>>>(Qb, Kb, Vb, A);
        vlin_kernel<<<kT, 256, 0, stream>>>(A, Wo + l * kD * kD, bo + l * kDG, Qb);
        resmn_kernel<<<kT * kD / 8, 256, 0, stream>>>(X, Qb, gm1 + l * kDG);
        ln2d_kernel<<<kT, 256, 0, stream>>>(X, ln2w + l * kDG, ln2b + l * kDG, A);
        mlp_kernel<<<kT, 256, 0, stream>>>(A, W1 + l * kE * kD, b1 + l * kE * kG,
                                           W2 + l * kD * kE, b2 + l * kDG, Qb);
        resmn_kernel<<<kT * kD / 8, 256, 0, stream>>>(X, Qb, gm2 + l * kDG);
    }

    // delta / rot init / scan
    vlin_kernel<<<kT, 256, 0, stream>>>(X, Wr, br, A);
    rotinit_kernel<<<kT * kD / 8, 256, 0, stream>>>(A, Kb);
    float* pin = Kb;
    float* pout = Vb;
    for (int step = 1; step < kS; step <<= 1) {
        scan_kernel<<<kT * kD / 8, 256, 0, stream>>>(pin, pout, step);
        float* tmp = pin; pin = pout; pout = tmp;
    }
    // after 8 steps (step=1..128), pin == Kb
    cls_kernel<<<(kB * kNC + 255) / 256, 256, 0, stream>>>(pin, Wc, bc, (float*)d_out);
}

// Round 4
// 1156.456 us; speedup vs baseline: 4.1438x; 1.8422x over previous
//
#include <hip/hip_runtime.h>
#include <hip/hip_bf16.h>

// Problem constants (B=8, S=256, D=64, G=32, E=256, L=4, NH=8, DH=8)
constexpr int kB  = 8;
constexpr int kS  = 256;
constexpr int kD  = 64;
constexpr int kG  = 32;
constexpr int kE  = 256;
constexpr int kNH = 8;
constexpr int kHD = 256;              // DH*G = 8*32
constexpr int kDG = kD * kG;          // 2048
constexpr int kT  = kB * kS;          // 2048 tokens
constexpr int kNC = 1000;

using bf16x8 = __attribute__((ext_vector_type(8))) short;
using f32x4  = __attribute__((ext_vector_type(4))) float;

__device__ __forceinline__ short f2bf(float f) {
    unsigned u = __float_as_uint(f);
    unsigned r = (u + 0x7FFFu + ((u >> 16) & 1u)) >> 16;   // RNE
    return (short)r;
}

__device__ __forceinline__ float tanh_fast(float x) {
    float a = fabsf(x);
    float e = __expf(-2.f * a);
    float t = (1.f - e) / (1.f + e);
    return copysignf(t, x);
}

// ---------------- copy input residual stream into mutable ws ----------------
__global__ __launch_bounds__(256) void copy_kernel(const float* __restrict__ in,
                                                   float* __restrict__ out, int n) {
    int i = blockIdx.x * 256 + threadIdx.x;
    if (i < n) out[i] = in[i];
}

// ---------------- layer_norm2d over (D,G) per token ----------------
__global__ __launch_bounds__(256) void ln2d_kernel(const float* __restrict__ X,
                                                   const float* __restrict__ w,
                                                   const float* __restrict__ b,
                                                   float* __restrict__ Out) {
    int t = blockIdx.x, tid = threadIdx.x;
    const float* xp = X + (size_t)t * kDG;
    __shared__ float r1[256], r2[256];
    float v[8], s = 0.f, ss = 0.f;
#pragma unroll
    for (int j = 0; j < 8; j++) {
        float x = xp[tid + j * 256];
        v[j] = x; s += x; ss += x * x;
    }
    r1[tid] = s; r2[tid] = ss; __syncthreads();
    for (int o = 128; o > 0; o >>= 1) {
        if (tid < o) { r1[tid] += r1[tid + o]; r2[tid] += r2[tid + o]; }
        __syncthreads();
    }
    float mean = r1[0] * (1.f / kDG);
    float var  = r2[0] * (1.f / kDG) - mean * mean;
    float rstd = rsqrtf(var + 1e-5f);
    float* op = Out + (size_t)t * kDG;
#pragma unroll
    for (int j = 0; j < 8; j++) {
        int jj = tid + j * 256;
        op[jj] = (v[j] - mean) * rstd * w[jj] + b[jj];
    }
}

// ---------------- scalar fp32 versor_linear (kept ONLY for final Wr: scan-tree
// error analysis — 256 leaves add — forbids bf16 here) ----------------
__global__ __launch_bounds__(256) void vlin_kernel(const float* __restrict__ X,
                                                   const float* __restrict__ W,
                                                   const float* __restrict__ bias,
                                                   float* __restrict__ Out) {
    __shared__ float sx[kDG];      // 8 KB
    __shared__ float sw[kD * kD];  // 16 KB
    int t = blockIdx.x, tid = threadIdx.x;
    const float* xp = X + (size_t)t * kDG;
    for (int j = tid; j < kDG; j += 256) sx[j] = xp[j];
    for (int j = tid; j < kD * kD; j += 256) sw[j] = W[j];
    __syncthreads();
    int g = tid & 31, ob = tid >> 5;
    float* op = Out + (size_t)t * kDG;
    for (int o = ob; o < kD; o += 8) {
        float acc = bias[o * kG + g];
        const float* wr = sw + o * kD;
#pragma unroll
        for (int i = 0; i < kD; i++) acc += wr[i] * sx[i * kG + g];
        op[o * kG + g] = acc;
    }
}

// ---------------- MFMA GEMM over (t,g) columns ----------------
// out[t,o,g] = act(sum_i W[o,i]*X[t,i,g] + b[o,g]).  K=64.  4 tokens/block,
// one token per wave.  MLP1OUT: tanh + bf16 out in [t][g][e] layout.
template<int MT, bool MLP1OUT>
__global__ __launch_bounds__(256, 2) void gemm_tg_kernel(
    const float* __restrict__ X, const float* __restrict__ W,
    const float* __restrict__ bias, float* __restrict__ outF,
    unsigned short* __restrict__ outH) {
    constexpr int M = MT * 16;
    constexpr int WS = 64 + 8;                 // W row stride (bf16), 16B-aligned, 2-way max
    __shared__ short sW[M * WS];
    __shared__ short sXT[4][32][WS];           // per-wave token, [g][i]

    const int tid = threadIdx.x, wave = tid >> 6, lane = tid & 63;
    const int l16 = lane & 15, quad = lane >> 4;
    const int tok = blockIdx.x * 4 + wave;

    // stage W fp32->bf16 (cooperative, coalesced)
    for (int j = tid * 4; j < M * 64; j += 1024) {
        const float4 w4 = *(const float4*)(W + j);
        int o = j >> 6, i = j & 63;
        *(short4*)&sW[o * WS + i] = make_short4(f2bf(w4.x), f2bf(w4.y), f2bf(w4.z), f2bf(w4.w));
    }
    // stage own token transposed: sXT[wave][g][i]  (same-wave produce/consume)
    {
        const int g4 = (lane & 7) * 4;
        const int i0 = (lane >> 3) * 8;
        const float* xp = X + (size_t)tok * kDG;
#pragma unroll
        for (int half = 0; half < 2; ++half) {
            float4 vr[4];
#pragma unroll
            for (int r = 0; r < 4; ++r)
                vr[r] = *(const float4*)(xp + (i0 + half * 4 + r) * kG + g4);
#pragma unroll
            for (int gg = 0; gg < 4; ++gg)
                *(short4*)&sXT[wave][g4 + gg][i0 + half * 4] =
                    make_short4(f2bf((&vr[0].x)[gg]), f2bf((&vr[1].x)[gg]),
                                f2bf((&vr[2].x)[gg]), f2bf((&vr[3].x)[gg]));
        }
    }
    __syncthreads();   // sW ready

    bf16x8 bfr[2][2];  // [k-chunk][n-tile]
#pragma unroll
    for (int c = 0; c < 2; ++c)
#pragma unroll
        for (int nt = 0; nt < 2; ++nt)
            bfr[c][nt] = *(const bf16x8*)&sXT[wave][nt * 16 + l16][c * 32 + quad * 8];

    f32x4 acc[MT][2];
#pragma unroll
    for (int mt = 0; mt < MT; ++mt)
#pragma unroll
        for (int nt = 0; nt < 2; ++nt) acc[mt][nt] = (f32x4){0.f, 0.f, 0.f, 0.f};

#pragma unroll
    for (int mt = 0; mt < MT; ++mt)
#pragma unroll
        for (int c = 0; c < 2; ++c) {
            bf16x8 afr = *(const bf16x8*)&sW[(mt * 16 + l16) * WS + c * 32 + quad * 8];
#pragma unroll
            for (int nt = 0; nt < 2; ++nt)
                acc[mt][nt] = __builtin_amdgcn_mfma_f32_16x16x32_bf16(afr, bfr[c][nt], acc[mt][nt], 0, 0, 0);
        }

    if (!MLP1OUT) {
        float* op = outF + (size_t)tok * M * kG;
#pragma unroll
        for (int mt = 0; mt < MT; ++mt)
#pragma unroll
            for (int nt = 0; nt < 2; ++nt) {
                int g = nt * 16 + l16;
#pragma unroll
                for (int r = 0; r < 4; ++r) {
                    int o = mt * 16 + quad * 4 + r;
                    op[o * kG + g] = acc[mt][nt][r] + bias[o * kG + g];
                }
            }
    } else {
        unsigned short* op = outH + (size_t)tok * M * kG;   // [t][g][M]
#pragma unroll
        for (int mt = 0; mt < MT; ++mt)
#pragma unroll
            for (int nt = 0; nt < 2; ++nt) {
                int g = nt * 16 + l16;
                int e0 = mt * 16 + quad * 4;
                short4 s4;
                s4.x = f2bf(tanh_fast(acc[mt][nt][0] + bias[(e0 + 0) * kG + g]));
                s4.y = f2bf(tanh_fast(acc[mt][nt][1] + bias[(e0 + 1) * kG + g]));
                s4.z = f2bf(tanh_fast(acc[mt][nt][2] + bias[(e0 + 2) * kG + g]));
                s4.w = f2bf(tanh_fast(acc[mt][nt][3] + bias[(e0 + 3) * kG + g]));
                *(short4*)&op[g * M + e0] = s4;
            }
    }
}

// ---------------- MLP second half: out[t,o,g] = sum_e W2[o,e]*m[t,g,e] + b2 ----
// B-fragments load straight from global (m is bf16 [t][g][e], contiguous in e).
__global__ __launch_bounds__(256, 2) void mlp2_kernel(
    const unsigned short* __restrict__ Mb,  // [t][32][256] bf16
    const float* __restrict__ W2,           // [64][256]
    const float* __restrict__ b2,           // [64][32]
    float* __restrict__ Out) {              // [t][64][32]
    constexpr int WS = 256 + 8;             // 264
    __shared__ short sW[64 * WS];           // 33.8 KB
    const int tid = threadIdx.x, wave = tid >> 6, lane = tid & 63;
    const int l16 = lane & 15, quad = lane >> 4;
    const int tok = blockIdx.x * 4 + wave;

    for (int j = tid * 4; j < 64 * 256; j += 1024) {
        const float4 w4 = *(const float4*)(W2 + j);
        int o = j >> 8, i = j & 255;
        *(short4*)&sW[o * WS + i] = make_short4(f2bf(w4.x), f2bf(w4.y), f2bf(w4.z), f2bf(w4.w));
    }
    __syncthreads();

    f32x4 acc[4][2];
#pragma unroll
    for (int mt = 0; mt < 4; ++mt)
#pragma unroll
        for (int nt = 0; nt < 2; ++nt) acc[mt][nt] = (f32x4){0.f, 0.f, 0.f, 0.f};

    const unsigned short* mp = Mb + (size_t)tok * kG * kE;
#pragma unroll
    for (int c = 0; c < 8; ++c) {
        bf16x8 bfr[2];
#pragma unroll
        for (int nt = 0; nt < 2; ++nt)
            bfr[nt] = *(const bf16x8*)&mp[(nt * 16 + l16) * kE + c * 32 + quad * 8];
#pragma unroll
        for (int mt = 0; mt < 4; ++mt) {
            bf16x8 afr = *(const bf16x8*)&sW[(mt * 16 + l16) * WS + c * 32 + quad * 8];
#pragma unroll
            for (int nt = 0; nt < 2; ++nt)
                acc[mt][nt] = __builtin_amdgcn_mfma_f32_16x16x32_bf16(afr, bfr[nt], acc[mt][nt], 0, 0, 0);
        }
    }

    float* op = Out + (size_t)tok * kDG;
#pragma unroll
    for (int mt = 0; mt < 4; ++mt)
#pragma unroll
        for (int nt = 0; nt < 2; ++nt) {
            int g = nt * 16 + l16;
#pragma unroll
            for (int r = 0; r < 4; ++r) {
                int o = mt * 16 + quad * 4 + r;
                op[o * kG + g] = acc[mt][nt][r] + b2[o * kG + g];
            }
        }
}

// ---------------- MFMA flash-style attention ----------------
constexpr int QSTR = 264;   // bf16 row stride for Qs/Ps and K tiles
constexpr int VSTR = 40;    // bf16 row stride for VsT

__global__ __launch_bounds__(256) void attn_mfma_kernel(const float* __restrict__ Q,
                                                        const float* __restrict__ K,
                                                        const float* __restrict__ V,
                                                        float* __restrict__ O) {
    __shared__ short sQ[64 * QSTR];
    __shared__ short sKV[256 * VSTR];

    const int qt = blockIdx.x, h = blockIdx.y, b = blockIdx.z;
    const int tid = threadIdx.x;
    const int wave = tid >> 6, lane = tid & 63;
    const int l16 = lane & 15, quad = lane >> 4;

    const size_t bh = (size_t)b * kS * kDG + (size_t)h * kHD;

    {
        int r0 = tid >> 6;
        int c4 = lane << 2;
        for (int it = 0; it < 16; ++it) {
            int row = it * 4 + r0;
            const float4 v = *(const float4*)(Q + bh + (size_t)(qt * 64 + row) * kDG + c4);
            short4 p = make_short4(f2bf(v.x), f2bf(v.y), f2bf(v.z), f2bf(v.w));
            *(short4*)&sQ[row * QSTR + c4] = p;
        }
    }
    __syncthreads();

    bf16x8 afrag[8];
    {
        int row = wave * 16 + l16;
#pragma unroll
        for (int c = 0; c < 8; ++c)
            afrag[c] = *(const bf16x8*)&sQ[row * QSTR + c * 32 + quad * 8];
    }

    f32x4 acc[16];
#pragma unroll
    for (int i = 0; i < 16; ++i) acc[i] = (f32x4){0.f, 0.f, 0.f, 0.f};

    for (int kt = 0; kt < 8; ++kt) {
        __syncthreads();
        {
            int r0 = tid >> 6;
            int c4 = lane << 2;
            for (int it = 0; it < 8; ++it) {
                int row = it * 4 + r0;
                const float4 v = *(const float4*)(K + bh + (size_t)(kt * 32 + row) * kDG + c4);
                short4 p = make_short4(f2bf(v.x), f2bf(v.y), f2bf(v.z), f2bf(v.w));
                *(short4*)&sKV[row * QSTR + c4] = p;
            }
        }
        __syncthreads();
#pragma unroll
        for (int nt = 0; nt < 2; ++nt) {
            int key = nt * 16 + l16;
            f32x4 a = acc[kt * 2 + nt];
#pragma unroll
            for (int c = 0; c < 8; ++c) {
                bf16x8 bfrag = *(const bf16x8*)&sKV[key * QSTR + c * 32 + quad * 8];
                a = __builtin_amdgcn_mfma_f32_16x16x32_bf16(afrag[c], bfrag, a, 0, 0, 0);
            }
            acc[kt * 2 + nt] = a;
        }
    }
    __syncthreads();

    float inv[4];
#pragma unroll
    for (int r = 0; r < 4; ++r) {
        float m = -1e30f;
#pragma unroll
        for (int t = 0; t < 16; ++t) m = fmaxf(m, acc[t][r]);
#pragma unroll
        for (int off = 1; off < 16; off <<= 1) m = fmaxf(m, __shfl_xor(m, off, 16));
        float s = 0.f;
#pragma unroll
        for (int t = 0; t < 16; ++t) {
            float p = __expf((acc[t][r] - m) * 0.0625f);
            acc[t][r] = p; s += p;
        }
#pragma unroll
        for (int off = 1; off < 16; off <<= 1) s += __shfl_xor(s, off, 16);
        inv[r] = 1.f / s;
    }

#pragma unroll
    for (int t = 0; t < 16; ++t)
#pragma unroll
        for (int r = 0; r < 4; ++r)
            sQ[(wave * 16 + quad * 4 + r) * QSTR + t * 16 + l16] = f2bf(acc[t][r]);

    f32x4 oacc[16];
#pragma unroll
    for (int i = 0; i < 16; ++i) oacc[i] = (f32x4){0.f, 0.f, 0.f, 0.f};

    for (int vt = 0; vt < 8; ++vt) {
        __syncthreads();
        {
            int kb = tid >> 5;
            for (int it = 0; it < 2; ++it) {
                int db = (tid & 31) + it * 32;
                float4 vr[4];
#pragma unroll
                for (int r = 0; r < 4; ++r)
                    vr[r] = *(const float4*)(V + bh + (size_t)(vt * 32 + kb * 4 + r) * kDG + db * 4);
#pragma unroll
                for (int i = 0; i < 4; ++i) {
                    short4 p = make_short4(f2bf((&vr[0].x)[i]), f2bf((&vr[1].x)[i]),
                                           f2bf((&vr[2].x)[i]), f2bf((&vr[3].x)[i]));
                    *(short4*)&sKV[(db * 4 + i) * VSTR + kb * 4] = p;
                }
            }
        }
        __syncthreads();
        bf16x8 pfrag = *(const bf16x8*)&sQ[(wave * 16 + l16) * QSTR + vt * 32 + quad * 8];
#pragma unroll
        for (int dt = 0; dt < 16; ++dt) {
            bf16x8 vfrag = *(const bf16x8*)&sKV[(dt * 16 + l16) * VSTR + quad * 8];
            oacc[dt] = __builtin_amdgcn_mfma_f32_16x16x32_bf16(pfrag, vfrag, oacc[dt], 0, 0, 0);
        }
    }

    {
        int qrow = qt * 64 + wave * 16 + quad * 4;
#pragma unroll
        for (int dt = 0; dt < 16; ++dt)
#pragma unroll
            for (int r = 0; r < 4; ++r)
                O[bh + (size_t)(qrow + r) * kDG + dt * 16 + l16] = oacc[dt][r] * inv[r];
    }
}

// ---------------- residual + manifold_norm: X = mn(X + gamma*H) ----------------
__global__ __launch_bounds__(256) void resmn_kernel(float* __restrict__ X,
                                                    const float* __restrict__ H,
                                                    const float* __restrict__ gamma) {
    int gid = blockIdx.x * 8 + (threadIdx.x >> 5);
    int lane = threadIdx.x & 31;
    int d = gid % kD;
    size_t idx = (size_t)gid * kG + lane;
    float v = X[idx] + gamma[d * kG + lane] * H[idx];
    float sq = v * v;
#pragma unroll
    for (int m = 16; m > 0; m >>= 1) sq += __shfl_xor(sq, m, 32);
    X[idx] = v / (sqrtf(sq) + 1e-6f);
}

// ---------------- rot init: R = mn(0.5*delta + e0) ----------------
__global__ __launch_bounds__(256) void rotinit_kernel(const float* __restrict__ A,
                                                      float* __restrict__ R) {
    int gid = blockIdx.x * 8 + (threadIdx.x >> 5);
    int lane = threadIdx.x & 31;
    size_t idx = (size_t)gid * kG + lane;
    float v = 0.5f * A[idx] + (lane == 0 ? 1.0f : 0.0f);
    float sq = v * v;
#pragma unroll
    for (int m = 16; m > 0; m >>= 1) sq += __shfl_xor(sq, m, 32);
    R[idx] = v / (sqrtf(sq) + 1e-6f);
}

// ---------------- scan step ----------------
__global__ __launch_bounds__(256) void scan_kernel(const float* __restrict__ In,
                                                   float* __restrict__ Out, int step) {
    __shared__ float sgn[1024];
    int tid = threadIdx.x;
    for (int q = tid; q < 1024; q += 256) {
        int a = q >> 5, k = q & 31, bb = a ^ k;
        int ssum = 0;
        for (int tt = a >> 1; tt; tt >>= 1) ssum += __popc(tt & bb);
        ssum += (a & bb) >> 4;
        sgn[q] = (ssum & 1) ? -1.f : 1.f;
    }
    __syncthreads();
    int gid = blockIdx.x * 8 + (tid >> 5);
    int lane = tid & 31;
    int s = (gid / kD) % kS;
    size_t idx = (size_t)gid * kG + lane;
    float xk = In[idx];
    if (s < step) { Out[idx] = xk; return; }
    float yk = In[idx - (size_t)step * kDG];
    float acc = 0.f;
#pragma unroll
    for (int a = 0; a < 32; a++) {
        float xa = __shfl(xk, a, 32);
        float yb = __shfl(yk, a ^ lane, 32);
        acc += sgn[a * 32 + lane] * xa * yb;
    }
    float sq = acc * acc;
#pragma unroll
    for (int m = 16; m > 0; m >>= 1) sq += __shfl_xor(sq, m, 32);
    Out[idx] = acc / (sqrtf(sq) + 1e-6f);
}

// ---------------- classifier ----------------
__global__ __launch_bounds__(256) void cls_kernel(const float* __restrict__ R,
                                                  const float* __restrict__ Wc,
                                                  const float* __restrict__ bc,
                                                  float* __restrict__ out) {
    int idx = blockIdx.x * 256 + threadIdx.x;
    if (idx >= kB * kNC) return;
    int b = idx / kNC, c = idx % kNC;
    const float* p = R + ((size_t)(b * kS + kS - 1)) * kDG;
    const float* w = Wc + (size_t)c * kDG;
    float acc = bc[c];
#pragma unroll 8
    for (int j = 0; j < kDG; j++) acc += p[j] * w[j];
    out[idx] = acc;
}

extern "C" void kernel_launch(void* const* d_in, const int* in_sizes, int n_in,
                              void* d_out, int out_size, void* d_ws, size_t ws_size,
                              hipStream_t stream) {
    const float* x_in = (const float*)d_in[0];
    const float* Wq   = (const float*)d_in[1];
    const float* bq   = (const float*)d_in[2];
    const float* Wk   = (const float*)d_in[3];
    const float* bk   = (const float*)d_in[4];
    const float* Wv   = (const float*)d_in[5];
    const float* bv   = (const float*)d_in[6];
    const float* Wo   = (const float*)d_in[7];
    const float* bo   = (const float*)d_in[8];
    const float* ln1w = (const float*)d_in[9];
    const float* ln1b = (const float*)d_in[10];
    const float* ln2w = (const float*)d_in[11];
    const float* ln2b = (const float*)d_in[12];
    const float* gm1  = (const float*)d_in[13];
    const float* gm2  = (const float*)d_in[14];
    const float* W1   = (const float*)d_in[15];
    const float* b1   = (const float*)d_in[16];
    const float* W2   = (const float*)d_in[17];
    const float* b2   = (const float*)d_in[18];
    const float* Wr   = (const float*)d_in[19];
    const float* br   = (const float*)d_in[20];
    const float* Wc   = (const float*)d_in[21];
    const float* bc   = (const float*)d_in[22];

    const size_t NEL = (size_t)kT * kDG;   // 4M elements per activation buffer
    float* F  = (float*)d_ws;
    float* X  = F;
    float* A  = F + NEL;
    float* Qb = F + 2 * NEL;
    float* Kb = F + 3 * NEL;
    float* Vb = F + 4 * NEL;
    // bf16 MLP intermediate [t][32][256] = 33.5 MB, reuses Kb+Vb (free during MLP)
    unsigned short* Mb = (unsigned short*)Kb;

    copy_kernel<<<(int)(NEL / 256), 256, 0, stream>>>(x_in, X, (int)NEL);

    for (int l = 0; l < 4; l++) {
        ln2d_kernel<<<kT, 256, 0, stream>>>(X, ln1w + l * kDG, ln1b + l * kDG, A);
        gemm_tg_kernel<4, false><<<kT / 4, 256, 0, stream>>>(A, Wq + l * kD * kD, bq + l * kDG, Qb, nullptr);
        gemm_tg_kernel<4, false><<<kT / 4, 256, 0, stream>>>(A, Wk + l * kD * kD, bk + l * kDG, Kb, nullptr);
        gemm_tg_kernel<4, false><<<kT / 4, 256, 0, stream>>>(A, Wv + l * kD * kD, bv + l * kDG, Vb, nullptr);
        attn_mfma_kernel<<<dim3(4, kNH, kB), 256, 0, stream>>>(Qb, Kb, Vb, A);
        gemm_tg_kernel<4, false><<<kT / 4, 256, 0, stream>>>(A, Wo + l * kD * kD, bo + l * kDG, Qb, nullptr);
        resmn_kernel<<<kT * kD / 8, 256, 0, stream>>>(X, Qb, gm1 + l * kDG);
        ln2d_kernel<<<kT, 256, 0, stream>>>(X, ln2w + l * kDG, ln2b + l * kDG, A);
        gemm_tg_kernel<16, true><<<kT / 4, 256, 0, stream>>>(A, W1 + l * kE * kD, b1 + l * kE * kG, nullptr, Mb);
        mlp2_kernel<<<kT / 4, 256, 0, stream>>>(Mb, W2 + l * kD * kE, b2 + l * kDG, Qb);
        resmn_kernel<<<kT * kD / 8, 256, 0, stream>>>(X, Qb, gm2 + l * kDG);
    }

    // delta / rot init / scan — fp32 path (error-sensitive: 256 scan leaves add)
    vlin_kernel<<<kT, 256, 0, stream>>>(X, Wr, br, A);
    rotinit_kernel<<<kT * kD / 8, 256, 0, stream>>>(A, Kb);
    float* pin = Kb;
    float* pout = Vb;
    for (int step = 1; step < kS; step <<= 1) {
        scan_kernel<<<kT * kD / 8, 256, 0, stream>>>(pin, pout, step);
        float* tmp = pin; pin = pout; pout = tmp;
    }
    cls_kernel<<<(kB * kNC + 255) / 256, 256, 0, stream>>>(pin, Wc, bc, (float*)d_out);
}

// Round 6
// 715.964 us; speedup vs baseline: 6.6932x; 1.6152x over previous
//
#include <hip/hip_runtime.h>
#include <hip/hip_bf16.h>

// Problem constants (B=8, S=256, D=64, G=32, E=256, L=4, NH=8, DH=8)
constexpr int kB  = 8;
constexpr int kS  = 256;
constexpr int kD  = 64;
constexpr int kG  = 32;
constexpr int kE  = 256;
constexpr int kNH = 8;
constexpr int kHD = 256;              // DH*G = 8*32
constexpr int kDG = kD * kG;          // 2048
constexpr int kT  = kB * kS;          // 2048 tokens
constexpr int kNC = 1000;

using bf16x8 = __attribute__((ext_vector_type(8))) short;
using f32x4  = __attribute__((ext_vector_type(4))) float;

__device__ __forceinline__ short f2bf(float f) {
    unsigned u = __float_as_uint(f);
    unsigned r = (u + 0x7FFFu + ((u >> 16) & 1u)) >> 16;   // RNE
    return (short)r;
}

__device__ __forceinline__ float tanh_fast(float x) {
    float a = fabsf(x);
    float e = __expf(-2.f * a);
    float t = (1.f - e) / (1.f + e);
    return copysignf(t, x);
}

// ---------------- first LN fused with residual-stream copy ----------------
// X = x_in (copy), A = layer_norm2d(x_in)
__global__ __launch_bounds__(256) void lncopy_kernel(const float* __restrict__ Xin,
                                                     const float* __restrict__ w,
                                                     const float* __restrict__ b,
                                                     float* __restrict__ X,
                                                     float* __restrict__ A) {
    int t = blockIdx.x, tid = threadIdx.x;
    const float* xp = Xin + (size_t)t * kDG;
    __shared__ float r1[256], r2[256];
    float v[8], s = 0.f, ss = 0.f;
#pragma unroll
    for (int j = 0; j < 8; j++) {
        float x = xp[tid + j * 256];
        v[j] = x; s += x; ss += x * x;
    }
    r1[tid] = s; r2[tid] = ss; __syncthreads();
    for (int o = 128; o > 0; o >>= 1) {
        if (tid < o) { r1[tid] += r1[tid + o]; r2[tid] += r2[tid + o]; }
        __syncthreads();
    }
    float mean = r1[0] * (1.f / kDG);
    float var  = r2[0] * (1.f / kDG) - mean * mean;
    float rstd = rsqrtf(var + 1e-5f);
    float* xo = X + (size_t)t * kDG;
    float* ao = A + (size_t)t * kDG;
#pragma unroll
    for (int j = 0; j < 8; j++) {
        int jj = tid + j * 256;
        xo[jj] = v[j];
        ao[jj] = (v[j] - mean) * rstd * w[jj] + b[jj];
    }
}

// ---------------- residual + manifold_norm + next layer_norm (fused) -------
// X = mn(X + gamma*H)  (written back);  A = LN2d(X) * w + b
__global__ __launch_bounds__(256) void resmn_ln_kernel(float* __restrict__ X,
                                                       const float* __restrict__ H,
                                                       const float* __restrict__ gamma,
                                                       const float* __restrict__ w,
                                                       const float* __restrict__ b,
                                                       float* __restrict__ A) {
    int t = blockIdx.x, tid = threadIdx.x;
    int g8 = tid >> 5, lane = tid & 31;
    __shared__ float r1[256], r2[256];
    float xn[8];
    float s = 0.f, ss = 0.f;
#pragma unroll
    for (int j = 0; j < 8; j++) {
        int d = j * 8 + g8;
        size_t idx = (size_t)t * kDG + d * kG + lane;
        float v = X[idx] + gamma[d * kG + lane] * H[idx];
        float sq = v * v;
#pragma unroll
        for (int m = 16; m > 0; m >>= 1) sq += __shfl_xor(sq, m, 32);
        float xv = v / (sqrtf(sq) + 1e-6f);
        X[idx] = xv;
        xn[j] = xv;
        s += xv; ss += xv * xv;
    }
    r1[tid] = s; r2[tid] = ss; __syncthreads();
    for (int o = 128; o > 0; o >>= 1) {
        if (tid < o) { r1[tid] += r1[tid + o]; r2[tid] += r2[tid + o]; }
        __syncthreads();
    }
    float mean = r1[0] * (1.f / kDG);
    float var  = r2[0] * (1.f / kDG) - mean * mean;
    float rstd = rsqrtf(var + 1e-5f);
#pragma unroll
    for (int j = 0; j < 8; j++) {
        int d = j * 8 + g8;
        size_t idx = (size_t)t * kDG + d * kG + lane;
        A[idx] = (xn[j] - mean) * rstd * w[d * kG + lane] + b[d * kG + lane];
    }
}

// ---------------- plain residual + manifold_norm (last layer) ----------------
__global__ __launch_bounds__(256) void resmn_kernel(float* __restrict__ X,
                                                    const float* __restrict__ H,
                                                    const float* __restrict__ gamma) {
    int gid = blockIdx.x * 8 + (threadIdx.x >> 5);
    int lane = threadIdx.x & 31;
    int d = gid % kD;
    size_t idx = (size_t)gid * kG + lane;
    float v = X[idx] + gamma[d * kG + lane] * H[idx];
    float sq = v * v;
#pragma unroll
    for (int m = 16; m > 0; m >>= 1) sq += __shfl_xor(sq, m, 32);
    X[idx] = v / (sqrtf(sq) + 1e-6f);
}

// ---------------- scalar fp32 versor_linear (kept ONLY for final Wr: scan-tree
// error analysis — 256 leaves add — forbids bf16 here) ----------------
__global__ __launch_bounds__(256) void vlin_kernel(const float* __restrict__ X,
                                                   const float* __restrict__ W,
                                                   const float* __restrict__ bias,
                                                   float* __restrict__ Out) {
    __shared__ float sx[kDG];      // 8 KB
    __shared__ float sw[kD * kD];  // 16 KB
    int t = blockIdx.x, tid = threadIdx.x;
    const float* xp = X + (size_t)t * kDG;
    for (int j = tid; j < kDG; j += 256) sx[j] = xp[j];
    for (int j = tid; j < kD * kD; j += 256) sw[j] = W[j];
    __syncthreads();
    int g = tid & 31, ob = tid >> 5;
    float* op = Out + (size_t)t * kDG;
    for (int o = ob; o < kD; o += 8) {
        float acc = bias[o * kG + g];
        const float* wr = sw + o * kD;
#pragma unroll
        for (int i = 0; i < kD; i++) acc += wr[i] * sx[i * kG + g];
        op[o * kG + g] = acc;
    }
}

// ---------------- MFMA GEMM over (t,g) columns (Wo path / MLP1) -------------
template<int MT, bool MLP1OUT>
__global__ __launch_bounds__(256, 2) void gemm_tg_kernel(
    const float* __restrict__ X, const float* __restrict__ W,
    const float* __restrict__ bias, float* __restrict__ outF,
    unsigned short* __restrict__ outH) {
    constexpr int M = MT * 16;
    constexpr int WS = 64 + 8;                 // bf16 row stride
    __shared__ short sW[M * WS];
    __shared__ short sXT[4][32][WS];           // per-wave token, [g][i]

    const int tid = threadIdx.x, wave = tid >> 6, lane = tid & 63;
    const int l16 = lane & 15, quad = lane >> 4;
    const int tok = blockIdx.x * 4 + wave;

    for (int j = tid * 4; j < M * 64; j += 1024) {
        const float4 w4 = *(const float4*)(W + j);
        int o = j >> 6, i = j & 63;
        *(short4*)&sW[o * WS + i] = make_short4(f2bf(w4.x), f2bf(w4.y), f2bf(w4.z), f2bf(w4.w));
    }
    {
        const int g4 = (lane & 7) * 4;
        const int i0 = (lane >> 3) * 8;
        const float* xp = X + (size_t)tok * kDG;
#pragma unroll
        for (int half = 0; half < 2; ++half) {
            float4 vr[4];
#pragma unroll
            for (int r = 0; r < 4; ++r)
                vr[r] = *(const float4*)(xp + (i0 + half * 4 + r) * kG + g4);
#pragma unroll
            for (int gg = 0; gg < 4; ++gg)
                *(short4*)&sXT[wave][g4 + gg][i0 + half * 4] =
                    make_short4(f2bf((&vr[0].x)[gg]), f2bf((&vr[1].x)[gg]),
                                f2bf((&vr[2].x)[gg]), f2bf((&vr[3].x)[gg]));
        }
    }
    __syncthreads();

    bf16x8 bfr[2][2];
#pragma unroll
    for (int c = 0; c < 2; ++c)
#pragma unroll
        for (int nt = 0; nt < 2; ++nt)
            bfr[c][nt] = *(const bf16x8*)&sXT[wave][nt * 16 + l16][c * 32 + quad * 8];

    f32x4 acc[MT][2];
#pragma unroll
    for (int mt = 0; mt < MT; ++mt)
#pragma unroll
        for (int nt = 0; nt < 2; ++nt) acc[mt][nt] = (f32x4){0.f, 0.f, 0.f, 0.f};

#pragma unroll
    for (int mt = 0; mt < MT; ++mt)
#pragma unroll
        for (int c = 0; c < 2; ++c) {
            bf16x8 afr = *(const bf16x8*)&sW[(mt * 16 + l16) * WS + c * 32 + quad * 8];
#pragma unroll
            for (int nt = 0; nt < 2; ++nt)
                acc[mt][nt] = __builtin_amdgcn_mfma_f32_16x16x32_bf16(afr, bfr[c][nt], acc[mt][nt], 0, 0, 0);
        }

    if (!MLP1OUT) {
        float* op = outF + (size_t)tok * M * kG;
#pragma unroll
        for (int mt = 0; mt < MT; ++mt)
#pragma unroll
            for (int nt = 0; nt < 2; ++nt) {
                int g = nt * 16 + l16;
#pragma unroll
                for (int r = 0; r < 4; ++r) {
                    int o = mt * 16 + quad * 4 + r;
                    op[o * kG + g] = acc[mt][nt][r] + bias[o * kG + g];
                }
            }
    } else {
        unsigned short* op = outH + (size_t)tok * M * kG;   // [t][g][M]
#pragma unroll
        for (int mt = 0; mt < MT; ++mt)
#pragma unroll
            for (int nt = 0; nt < 2; ++nt) {
                int g = nt * 16 + l16;
                int e0 = mt * 16 + quad * 4;
                short4 s4;
                s4.x = f2bf(tanh_fast(acc[mt][nt][0] + bias[(e0 + 0) * kG + g]));
                s4.y = f2bf(tanh_fast(acc[mt][nt][1] + bias[(e0 + 1) * kG + g]));
                s4.z = f2bf(tanh_fast(acc[mt][nt][2] + bias[(e0 + 2) * kG + g]));
                s4.w = f2bf(tanh_fast(acc[mt][nt][3] + bias[(e0 + 3) * kG + g]));
                *(short4*)&op[g * M + e0] = s4;
            }
    }
}

// ---------------- fused Q/K/V GEMM (reads A once) ----------------
__global__ __launch_bounds__(256, 2) void gemm_qkv_kernel(
    const float* __restrict__ X,
    const float* __restrict__ Wq, const float* __restrict__ Wk, const float* __restrict__ Wv,
    const float* __restrict__ bq, const float* __restrict__ bk, const float* __restrict__ bv,
    float* __restrict__ Q, float* __restrict__ K, float* __restrict__ V) {
    constexpr int WS = 64 + 8;
    __shared__ short sW[3 * 64 * WS];          // 27.6 KB
    __shared__ short sXT[4][32][WS];           // 18.4 KB

    const int tid = threadIdx.x, wave = tid >> 6, lane = tid & 63;
    const int l16 = lane & 15, quad = lane >> 4;
    const int tok = blockIdx.x * 4 + wave;

    const float* Wp[3] = {Wq, Wk, Wv};
#pragma unroll
    for (int w = 0; w < 3; ++w)
        for (int j = tid * 4; j < 64 * 64; j += 1024) {
            const float4 w4 = *(const float4*)(Wp[w] + j);
            int o = j >> 6, i = j & 63;
            *(short4*)&sW[w * 64 * WS + o * WS + i] =
                make_short4(f2bf(w4.x), f2bf(w4.y), f2bf(w4.z), f2bf(w4.w));
        }
    {
        const int g4 = (lane & 7) * 4;
        const int i0 = (lane >> 3) * 8;
        const float* xp = X + (size_t)tok * kDG;
#pragma unroll
        for (int half = 0; half < 2; ++half) {
            float4 vr[4];
#pragma unroll
            for (int r = 0; r < 4; ++r)
                vr[r] = *(const float4*)(xp + (i0 + half * 4 + r) * kG + g4);
#pragma unroll
            for (int gg = 0; gg < 4; ++gg)
                *(short4*)&sXT[wave][g4 + gg][i0 + half * 4] =
                    make_short4(f2bf((&vr[0].x)[gg]), f2bf((&vr[1].x)[gg]),
                                f2bf((&vr[2].x)[gg]), f2bf((&vr[3].x)[gg]));
        }
    }
    __syncthreads();

    bf16x8 bfr[2][2];
#pragma unroll
    for (int c = 0; c < 2; ++c)
#pragma unroll
        for (int nt = 0; nt < 2; ++nt)
            bfr[c][nt] = *(const bf16x8*)&sXT[wave][nt * 16 + l16][c * 32 + quad * 8];

    f32x4 acc[3][4][2];
#pragma unroll
    for (int w = 0; w < 3; ++w)
#pragma unroll
        for (int mt = 0; mt < 4; ++mt)
#pragma unroll
            for (int nt = 0; nt < 2; ++nt) acc[w][mt][nt] = (f32x4){0.f, 0.f, 0.f, 0.f};

#pragma unroll
    for (int w = 0; w < 3; ++w)
#pragma unroll
        for (int mt = 0; mt < 4; ++mt)
#pragma unroll
            for (int c = 0; c < 2; ++c) {
                bf16x8 afr = *(const bf16x8*)&sW[w * 64 * WS + (mt * 16 + l16) * WS + c * 32 + quad * 8];
#pragma unroll
                for (int nt = 0; nt < 2; ++nt)
                    acc[w][mt][nt] = __builtin_amdgcn_mfma_f32_16x16x32_bf16(afr, bfr[c][nt], acc[w][mt][nt], 0, 0, 0);
            }

    float* Op[3] = {Q, K, V};
    const float* Bp[3] = {bq, bk, bv};
#pragma unroll
    for (int w = 0; w < 3; ++w) {
        float* op = Op[w] + (size_t)tok * kDG;
#pragma unroll
        for (int mt = 0; mt < 4; ++mt)
#pragma unroll
            for (int nt = 0; nt < 2; ++nt) {
                int g = nt * 16 + l16;
#pragma unroll
                for (int r = 0; r < 4; ++r) {
                    int o = mt * 16 + quad * 4 + r;
                    op[o * kG + g] = acc[w][mt][nt][r] + Bp[w][o * kG + g];
                }
            }
    }
}

// ---------------- MLP second half ----------------
__global__ __launch_bounds__(256, 2) void mlp2_kernel(
    const unsigned short* __restrict__ Mb,  // [t][32][256] bf16
    const float* __restrict__ W2,           // [64][256]
    const float* __restrict__ b2,           // [64][32]
    float* __restrict__ Out) {              // [t][64][32]
    constexpr int WS = 256 + 8;
    __shared__ short sW[64 * WS];
    const int tid = threadIdx.x, wave = tid >> 6, lane = tid & 63;
    const int l16 = lane & 15, quad = lane >> 4;
    const int tok = blockIdx.x * 4 + wave;

    for (int j = tid * 4; j < 64 * 256; j += 1024) {
        const float4 w4 = *(const float4*)(W2 + j);
        int o = j >> 8, i = j & 255;
        *(short4*)&sW[o * WS + i] = make_short4(f2bf(w4.x), f2bf(w4.y), f2bf(w4.z), f2bf(w4.w));
    }
    __syncthreads();

    f32x4 acc[4][2];
#pragma unroll
    for (int mt = 0; mt < 4; ++mt)
#pragma unroll
        for (int nt = 0; nt < 2; ++nt) acc[mt][nt] = (f32x4){0.f, 0.f, 0.f, 0.f};

    const unsigned short* mp = Mb + (size_t)tok * kG * kE;
#pragma unroll
    for (int c = 0; c < 8; ++c) {
        bf16x8 bfr[2];
#pragma unroll
        for (int nt = 0; nt < 2; ++nt)
            bfr[nt] = *(const bf16x8*)&mp[(nt * 16 + l16) * kE + c * 32 + quad * 8];
#pragma unroll
        for (int mt = 0; mt < 4; ++mt) {
            bf16x8 afr = *(const bf16x8*)&sW[(mt * 16 + l16) * WS + c * 32 + quad * 8];
#pragma unroll
            for (int nt = 0; nt < 2; ++nt)
                acc[mt][nt] = __builtin_amdgcn_mfma_f32_16x16x32_bf16(afr, bfr[nt], acc[mt][nt], 0, 0, 0);
        }
    }

    float* op = Out + (size_t)tok * kDG;
#pragma unroll
    for (int mt = 0; mt < 4; ++mt)
#pragma unroll
        for (int nt = 0; nt < 2; ++nt) {
            int g = nt * 16 + l16;
#pragma unroll
            for (int r = 0; r < 4; ++r) {
                int o = mt * 16 + quad * 4 + r;
                op[o * kG + g] = acc[mt][nt][r] + b2[o * kG + g];
            }
        }
}

// ---------------- MFMA flash-style attention ----------------
constexpr int QSTR = 264;
constexpr int VSTR = 40;

__global__ __launch_bounds__(256) void attn_mfma_kernel(const float* __restrict__ Q,
                                                        const float* __restrict__ K,
                                                        const float* __restrict__ V,
                                                        float* __restrict__ O) {
    __shared__ short sQ[64 * QSTR];
    __shared__ short sKV[256 * VSTR];

    const int qt = blockIdx.x, h = blockIdx.y, b = blockIdx.z;
    const int tid = threadIdx.x;
    const int wave = tid >> 6, lane = tid & 63;
    const int l16 = lane & 15, quad = lane >> 4;

    const size_t bh = (size_t)b * kS * kDG + (size_t)h * kHD;

    {
        int r0 = tid >> 6;
        int c4 = lane << 2;
        for (int it = 0; it < 16; ++it) {
            int row = it * 4 + r0;
            const float4 v = *(const float4*)(Q + bh + (size_t)(qt * 64 + row) * kDG + c4);
            short4 p = make_short4(f2bf(v.x), f2bf(v.y), f2bf(v.z), f2bf(v.w));
            *(short4*)&sQ[row * QSTR + c4] = p;
        }
    }
    __syncthreads();

    bf16x8 afrag[8];
    {
        int row = wave * 16 + l16;
#pragma unroll
        for (int c = 0; c < 8; ++c)
            afrag[c] = *(const bf16x8*)&sQ[row * QSTR + c * 32 + quad * 8];
    }

    f32x4 acc[16];
#pragma unroll
    for (int i = 0; i < 16; ++i) acc[i] = (f32x4){0.f, 0.f, 0.f, 0.f};

    for (int kt = 0; kt < 8; ++kt) {
        __syncthreads();
        {
            int r0 = tid >> 6;
            int c4 = lane << 2;
            for (int it = 0; it < 8; ++it) {
                int row = it * 4 + r0;
                const float4 v = *(const float4*)(K + bh + (size_t)(kt * 32 + row) * kDG + c4);
                short4 p = make_short4(f2bf(v.x), f2bf(v.y), f2bf(v.z), f2bf(v.w));
                *(short4*)&sKV[row * QSTR + c4] = p;
            }
        }
        __syncthreads();
#pragma unroll
        for (int nt = 0; nt < 2; ++nt) {
            int key = nt * 16 + l16;
            f32x4 a = acc[kt * 2 + nt];
#pragma unroll
            for (int c = 0; c < 8; ++c) {
                bf16x8 bfrag = *(const bf16x8*)&sKV[key * QSTR + c * 32 + quad * 8];
                a = __builtin_amdgcn_mfma_f32_16x16x32_bf16(afrag[c], bfrag, a, 0, 0, 0);
            }
            acc[kt * 2 + nt] = a;
        }
    }
    __syncthreads();

    float inv[4];
#pragma unroll
    for (int r = 0; r < 4; ++r) {
        float m = -1e30f;
#pragma unroll
        for (int t = 0; t < 16; ++t) m = fmaxf(m, acc[t][r]);
#pragma unroll
        for (int off = 1; off < 16; off <<= 1) m = fmaxf(m, __shfl_xor(m, off, 16));
        float s = 0.f;
#pragma unroll
        for (int t = 0; t < 16; ++t) {
            float p = __expf((acc[t][r] - m) * 0.0625f);
            acc[t][r] = p; s += p;
        }
#pragma unroll
        for (int off = 1; off < 16; off <<= 1) s += __shfl_xor(s, off, 16);
        inv[r] = 1.f / s;
    }

#pragma unroll
    for (int t = 0; t < 16; ++t)
#pragma unroll
        for (int r = 0; r < 4; ++r)
            sQ[(wave * 16 + quad * 4 + r) * QSTR + t * 16 + l16] = f2bf(acc[t][r]);

    f32x4 oacc[16];
#pragma unroll
    for (int i = 0; i < 16; ++i) oacc[i] = (f32x4){0.f, 0.f, 0.f, 0.f};

    for (int vt = 0; vt < 8; ++vt) {
        __syncthreads();
        {
            int kb = tid >> 5;
            for (int it = 0; it < 2; ++it) {
                int db = (tid & 31) + it * 32;
                float4 vr[4];
#pragma unroll
                for (int r = 0; r < 4; ++r)
                    vr[r] = *(const float4*)(V + bh + (size_t)(vt * 32 + kb * 4 + r) * kDG + db * 4);
#pragma unroll
                for (int i = 0; i < 4; ++i) {
                    short4 p = make_short4(f2bf((&vr[0].x)[i]), f2bf((&vr[1].x)[i]),
                                           f2bf((&vr[2].x)[i]), f2bf((&vr[3].x)[i]));
                    *(short4*)&sKV[(db * 4 + i) * VSTR + kb * 4] = p;
                }
            }
        }
        __syncthreads();
        bf16x8 pfrag = *(const bf16x8*)&sQ[(wave * 16 + l16) * QSTR + vt * 32 + quad * 8];
#pragma unroll
        for (int dt = 0; dt < 16; ++dt) {
            bf16x8 vfrag = *(const bf16x8*)&sKV[(dt * 16 + l16) * VSTR + quad * 8];
            oacc[dt] = __builtin_amdgcn_mfma_f32_16x16x32_bf16(pfrag, vfrag, oacc[dt], 0, 0, 0);
        }
    }

    {
        int qrow = qt * 64 + wave * 16 + quad * 4;
#pragma unroll
        for (int dt = 0; dt < 16; ++dt)
#pragma unroll
            for (int r = 0; r < 4; ++r)
                O[bh + (size_t)(qrow + r) * kDG + dt * 16 + l16] = oacc[dt][r] * inv[r];
    }
}

// ---------------- fused rotinit + cone-scan ----------------
// Only rot[:, -1] is consumed downstream.  The Kogge-Stone value at position
// 255 depends only on nodes N_i = {255 - j*2^i}; compute exactly those
// (255 gp ops per (b,d)) with the identical per-node arithmetic as the full
// scan -> bit-identical pooled result.  Block per (b,d); all levels in LDS.
__global__ __launch_bounds__(256) void scanfused_kernel(const float* __restrict__ Dl,
                                                        float* __restrict__ pooled) {
    __shared__ float big[256 * 32];   // 32 KB
    __shared__ float sml[128 * 32];   // 16 KB
    const int tid = threadIdx.x;
    const int b = blockIdx.x >> 6, d = blockIdx.x & 63;
    const int g8 = tid >> 5, lane = tid & 31;

    // per-lane sign bitmask: bit a = 1 iff GP_TABLE sign for (a, b=a^lane) < 0
    unsigned msk = 0;
#pragma unroll
    for (int a = 0; a < 32; ++a) {
        int bb = a ^ lane;
        int ssum = (a & bb) >> 4;                // SIG[4] = -1 metric term
        for (int tt = a >> 1; tt; tt >>= 1) ssum += __popc(tt & bb);
        msk |= (unsigned)(ssum & 1) << a;
    }

    // load delta + rotinit: v0[p] = mn(0.5*delta[p] + e0)
    const float* Dp = Dl + ((size_t)b * kS * kD + d) * kG;
    for (int it = 0; it < 32; ++it) {
        int p = it * 8 + g8;
        float v = 0.5f * Dp[(size_t)p * kDG + lane] + (lane == 0 ? 1.f : 0.f);
        float sq = v * v;
#pragma unroll
        for (int m = 16; m > 0; m >>= 1) sq += __shfl_xor(sq, m, 32);
        big[p * 32 + lane] = v / (sqrtf(sq) + 1e-6f);
    }
    __syncthreads();

    // level 1: sml[j] = mn(gp(v0[255-2j], v0[254-2j])), j = 0..127
    for (int it = 0; it < 16; ++it) {
        int j = it * 8 + g8;
        float x = big[(255 - 2 * j) * 32 + lane];
        float y = big[(254 - 2 * j) * 32 + lane];
        float acc = 0.f;
#pragma unroll
        for (int a = 0; a < 32; ++a) {
            float v = __shfl(x, a, 32) * __shfl_xor(y, a, 32);
            acc += __int_as_float(__float_as_int(v) ^ (int)((msk >> a) << 31));
        }
        float sq = acc * acc;
#pragma unroll
        for (int m = 16; m > 0; m >>= 1) sq += __shfl_xor(sq, m, 32);
        sml[j * 32 + lane] = acc / (sqrtf(sq) + 1e-6f);
    }
    __syncthreads();

    // levels 2..8: out[j] = mn(gp(in[2j], in[2j+1])), ping-pong sml<->big
    // (no LDS-pointer array: addrspace(3) static init is rejected by gfx950 BE)
    int pi = 0;
    for (int n = 64; n >= 1; n >>= 1) {
        float* in  = pi ? big : sml;
        float* out = pi ? sml : big;
        for (int j = g8; j < n; j += 8) {
            float x = in[(2 * j) * 32 + lane];
            float y = in[(2 * j + 1) * 32 + lane];
            float acc = 0.f;
#pragma unroll
            for (int a = 0; a < 32; ++a) {
                float v = __shfl(x, a, 32) * __shfl_xor(y, a, 32);
                acc += __int_as_float(__float_as_int(v) ^ (int)((msk >> a) << 31));
            }
            float sq = acc * acc;
#pragma unroll
            for (int m = 16; m > 0; m >>= 1) sq += __shfl_xor(sq, m, 32);
            out[j * 32 + lane] = acc / (sqrtf(sq) + 1e-6f);
        }
        __syncthreads();
        pi ^= 1;
    }
    // 7 transitions: final value sits in (pi ? big : sml) row 0
    if (tid < 32) {
        const float* fin = pi ? big : sml;
        pooled[((size_t)b * kD + d) * kG + lane] = fin[lane];
    }
}

// ---------------- classifier: wave per class, pooled staged in LDS ----------
__global__ __launch_bounds__(256) void cls2_kernel(const float* __restrict__ P,   // [8][2048]
                                                   const float* __restrict__ Wc,
                                                   const float* __restrict__ bc,
                                                   float* __restrict__ out) {
    __shared__ float sp[kB * kDG];   // 64 KB
    const int tid = threadIdx.x, wave = tid >> 6, lane = tid & 63;
    for (int j = tid * 4; j < kB * kDG; j += 1024)
        *(float4*)&sp[j] = *(const float4*)(P + j);
    __syncthreads();

    const int c = blockIdx.x * 4 + wave;
    const float* w = Wc + (size_t)c * kDG;
    float acc[kB];
#pragma unroll
    for (int b = 0; b < kB; ++b) acc[b] = 0.f;
#pragma unroll
    for (int cc = 0; cc < 8; ++cc) {
        const float4 w4 = *(const float4*)(w + cc * 256 + lane * 4);
#pragma unroll
        for (int b = 0; b < kB; ++b) {
            const float4 p4 = *(const float4*)&sp[b * kDG + cc * 256 + lane * 4];
            acc[b] += w4.x * p4.x + w4.y * p4.y + w4.z * p4.z + w4.w * p4.w;
        }
    }
#pragma unroll
    for (int b = 0; b < kB; ++b)
#pragma unroll
        for (int off = 32; off > 0; off >>= 1) acc[b] += __shfl_xor(acc[b], off, 64);
    if (lane == 0) {
        float bias = bc[c];
#pragma unroll
        for (int b = 0; b < kB; ++b) out[b * kNC + c] = acc[b] + bias;
    }
}

extern "C" void kernel_launch(void* const* d_in, const int* in_sizes, int n_in,
                              void* d_out, int out_size, void* d_ws, size_t ws_size,
                              hipStream_t stream) {
    const float* x_in = (const float*)d_in[0];
    const float* Wq   = (const float*)d_in[1];
    const float* bq   = (const float*)d_in[2];
    const float* Wk   = (const float*)d_in[3];
    const float* bk   = (const float*)d_in[4];
    const float* Wv   = (const float*)d_in[5];
    const float* bv   = (const float*)d_in[6];
    const float* Wo   = (const float*)d_in[7];
    const float* bo   = (const float*)d_in[8];
    const float* ln1w = (const float*)d_in[9];
    const float* ln1b = (const float*)d_in[10];
    const float* ln2w = (const float*)d_in[11];
    const float* ln2b = (const float*)d_in[12];
    const float* gm1  = (const float*)d_in[13];
    const float* gm2  = (const float*)d_in[14];
    const float* W1   = (const float*)d_in[15];
    const float* b1   = (const float*)d_in[16];
    const float* W2   = (const float*)d_in[17];
    const float* b2   = (const float*)d_in[18];
    const float* Wr   = (const float*)d_in[19];
    const float* br   = (const float*)d_in[20];
    const float* Wc   = (const float*)d_in[21];
    const float* bc   = (const float*)d_in[22];

    const size_t NEL = (size_t)kT * kDG;
    float* F  = (float*)d_ws;
    float* X  = F;
    float* A  = F + NEL;
    float* Qb = F + 2 * NEL;
    float* Kb = F + 3 * NEL;
    float* Vb = F + 4 * NEL;
    unsigned short* Mb = (unsigned short*)Kb;   // bf16 [t][32][256], reuses Kb+Vb
    float* pooled = Qb;                         // 16K floats, Qb free at scan time

    lncopy_kernel<<<kT, 256, 0, stream>>>(x_in, ln1w, ln1b, X, A);

    for (int l = 0; l < 4; l++) {
        gemm_qkv_kernel<<<kT / 4, 256, 0, stream>>>(A,
            Wq + l * kD * kD, Wk + l * kD * kD, Wv + l * kD * kD,
            bq + l * kDG, bk + l * kDG, bv + l * kDG, Qb, Kb, Vb);
        attn_mfma_kernel<<<dim3(4, kNH, kB), 256, 0, stream>>>(Qb, Kb, Vb, A);
        gemm_tg_kernel<4, false><<<kT / 4, 256, 0, stream>>>(A, Wo + l * kD * kD, bo + l * kDG, Qb, nullptr);
        resmn_ln_kernel<<<kT, 256, 0, stream>>>(X, Qb, gm1 + l * kDG, ln2w + l * kDG, ln2b + l * kDG, A);
        gemm_tg_kernel<16, true><<<kT / 4, 256, 0, stream>>>(A, W1 + l * kE * kD, b1 + l * kE * kG, nullptr, Mb);
        mlp2_kernel<<<kT / 4, 256, 0, stream>>>(Mb, W2 + l * kD * kE, b2 + l * kDG, Qb);
        if (l < 3)
            resmn_ln_kernel<<<kT, 256, 0, stream>>>(X, Qb, gm2 + l * kDG,
                ln1w + (l + 1) * kDG, ln1b + (l + 1) * kDG, A);
        else
            resmn_kernel<<<kT * kD / 8, 256, 0, stream>>>(X, Qb, gm2 + l * kDG);
    }

    // delta (fp32, error-sensitive) -> fused rotinit+cone-scan -> classifier
    vlin_kernel<<<kT, 256, 0, stream>>>(X, Wr, br, A);
    scanfused_kernel<<<kB * kD, 256, 0, stream>>>(A, pooled);
    cls2_kernel<<<kNC / 4, 256, 0, stream>>>(pooled, Wc, bc, (float*)d_out);
}